// Round 15
// baseline (216.577 us; speedup 1.0000x reference)
//
#include <hip/hip_runtime.h>

// Guided filter r=8 (K=17), eps=0.1, (8,3,1024,1024); f32 in / f32 out.
// V7: 64x32 tile (halo amortization), 4-plane arena 48x[stride 100] f32
// (76.8 KB, 2 blocks/CU), conflict-free maps, 4 barriers.
//
//   A : vertical 17-tap sliding sums of {I,p,I*p,I*I} -> planes 0..3
//       vs region 48 rows x 96 cols (img cols tx0-16..tx0+79), 384 units
//       (96 cols x 4 chunks of 12 rows), 1.5 passes over 256 threads
//   B1: horizontal 17-sums (window 32 cols, 16 out) of 4 planes -> a,b;
//       barrier; write a,b over planes 0,1 (ab cols 0..79 ~ img tx0-8..+71)
//   B2: horizontal 17-sums of a,b -> hs (64 cols) -> planes 2,3
//   C : vertical 17-sums of hs + finale (8 px/thread)

#define TW 64
#define TH 32
#define VCOLS 96
#define VROWS 48
#define STRD 100                   // words per arena row
#define SF4 25                     // float4 stride
#define PL (VROWS * STRD)          // 4800 words/plane
#define PL4 (PL / 4)               // 1200 f4/plane
#define INV_AREA (1.0f / 289.0f)
#define EPS 0.1f

__device__ __forceinline__ int refl1024(int v) {
    v = (v < 0) ? -v : v;
    v = (v > 1023) ? 2046 - v : v;
    if (v < 0) v = 0;
    if (v > 1023) v = 1023;
    return v;
}

__global__ __launch_bounds__(256) void gf_fused(
    const float* __restrict__ P, const float* __restrict__ I,
    float* __restrict__ O, int H, int W)
{
    __shared__ __align__(16) float4 S4[4 * PL4];   // 76800 B
    float* __restrict__ Sf = (float*)S4;

    const int tid = threadIdx.x;
    const int tx0 = blockIdx.x * TW;
    const int ty0 = blockIdx.y * TH;
    const size_t plane = (size_t)blockIdx.z * H * W;
    const float* __restrict__ Ic = I + plane;
    const float* __restrict__ Pc = P + plane;

    // ---------------- Phase A: vertical sliding sums ------------------------
    // unit u in [0,384): col = u%96 (vs col; img col tx0+col-16),
    //                    chunk = u/96 (12 vs-rows starting r0=chunk*12)
    {
        #pragma unroll
        for (int pass = 0; pass < 2; ++pass) {
            const int u = pass ? (256 + tid) : tid;
            if (pass == 0 || tid < 128) {
                const int chunk = u / 96;
                const int col   = u - chunk * 96;
                const int r0    = chunk * 12;
                const int gx    = refl1024(tx0 + col - 16);
                float vI[28], vP[28];
                #pragma unroll
                for (int j = 0; j < 28; ++j) {
                    const int gy = refl1024(ty0 + r0 - 16 + j);
                    const size_t g = (size_t)gy * W + gx;
                    vI[j] = Ic[g];
                    vP[j] = Pc[g];
                }
                float s0 = 0.f, s1 = 0.f, s2 = 0.f, s3 = 0.f;
                #pragma unroll
                for (int j = 0; j < 17; ++j) {
                    s0 += vI[j]; s1 += vP[j];
                    s2 += vI[j] * vP[j];
                    s3 += vI[j] * vI[j];
                }
                Sf[0 * PL + r0 * STRD + col] = s0;
                Sf[1 * PL + r0 * STRD + col] = s1;
                Sf[2 * PL + r0 * STRD + col] = s2;
                Sf[3 * PL + r0 * STRD + col] = s3;
                #pragma unroll
                for (int o = 1; o < 12; ++o) {
                    const float ni = vI[o + 16], oi = vI[o - 1];
                    const float np_ = vP[o + 16], op_ = vP[o - 1];
                    s0 += ni - oi;
                    s1 += np_ - op_;
                    s2 += ni * np_ - oi * op_;
                    s3 += ni * ni - oi * oi;
                    Sf[0 * PL + (r0 + o) * STRD + col] = s0;
                    Sf[1 * PL + (r0 + o) * STRD + col] = s1;
                    Sf[2 * PL + (r0 + o) * STRD + col] = s2;
                    Sf[3 * PL + (r0 + o) * STRD + col] = s3;
                }
            }
        }
    }
    __syncthreads();

    // ---------------- Phase B1: horizontal sums -> a,b ----------------------
    // 240 active threads: (row 0..47) x (cb 0..4), 16 ab-cols each.
    // ab arena col wa = cb*16+k  (img col tx0+wa-8); window vs cols [wa,wa+16].
    int row, cb; bool act;
    if (tid < 192) { row = (tid & 15) + ((tid >> 6) << 4); cb = (tid >> 4) & 3; act = true; }
    else           { row = tid - 192; cb = 4; act = (row < 48); }
    float oa[16], ob[16];
    if (act) {
        float sm0[16], sm1[16], sm2[16], sm3[16];
        #pragma unroll
        for (int q = 0; q < 4; ++q) {
            float vv[32];
            const int base = q * PL4 + row * SF4 + cb * 4;
            #pragma unroll
            for (int t = 0; t < 8; ++t) {
                const float4 w = S4[base + t];
                vv[4 * t + 0] = w.x; vv[4 * t + 1] = w.y;
                vv[4 * t + 2] = w.z; vv[4 * t + 3] = w.w;
            }
            float s = 0.f;
            #pragma unroll
            for (int j = 0; j < 17; ++j) s += vv[j];
            float* sm = (q == 0) ? sm0 : (q == 1) ? sm1 : (q == 2) ? sm2 : sm3;
            sm[0] = s;
            #pragma unroll
            for (int o = 1; o < 16; ++o) {
                s += vv[o + 16] - vv[o - 1];
                sm[o] = s;
            }
        }
        #pragma unroll
        for (int o = 0; o < 16; ++o) {
            const float mI  = sm0[o] * INV_AREA;
            const float mP  = sm1[o] * INV_AREA;
            const float mIp = sm2[o] * INV_AREA;
            const float mII = sm3[o] * INV_AREA;
            const float cov = mIp - mI * mP;
            const float var = mII - mI * mI;
            const float av  = cov / (var + EPS);
            oa[o] = av;
            ob[o] = mP - av * mI;
        }
    }
    __syncthreads();
    if (act) {
        const int base = row * SF4 + cb * 4;
        #pragma unroll
        for (int t = 0; t < 4; ++t) {
            S4[0 * PL4 + base + t] =
                make_float4(oa[4 * t], oa[4 * t + 1], oa[4 * t + 2], oa[4 * t + 3]);
            S4[1 * PL4 + base + t] =
                make_float4(ob[4 * t], ob[4 * t + 1], ob[4 * t + 2], ob[4 * t + 3]);
        }
    }
    __syncthreads();

    // ---------------- Phase B2: horizontal sums of a,b -> planes 2,3 --------
    // 192 threads: (row 0..47) x (cb 0..3), 16 hs-cols each.
    // hs col c = cb*16+k (img col tx0+c); window ab arena cols [c, c+16].
    if (tid < 192) {
        float qa[32], qb[32];
        const int base = row * SF4 + cb * 4;
        #pragma unroll
        for (int t = 0; t < 8; ++t) {
            const float4 wa = S4[0 * PL4 + base + t];
            const float4 wb = S4[1 * PL4 + base + t];
            qa[4 * t + 0] = wa.x; qa[4 * t + 1] = wa.y;
            qa[4 * t + 2] = wa.z; qa[4 * t + 3] = wa.w;
            qb[4 * t + 0] = wb.x; qb[4 * t + 1] = wb.y;
            qb[4 * t + 2] = wb.z; qb[4 * t + 3] = wb.w;
        }
        float hsA[16], hsB[16];
        float sa = 0.f, sb = 0.f;
        #pragma unroll
        for (int j = 0; j < 17; ++j) { sa += qa[j]; sb += qb[j]; }
        hsA[0] = sa; hsB[0] = sb;
        #pragma unroll
        for (int o = 1; o < 16; ++o) {
            sa += qa[o + 16] - qa[o - 1];
            sb += qb[o + 16] - qb[o - 1];
            hsA[o] = sa; hsB[o] = sb;
        }
        #pragma unroll
        for (int t = 0; t < 4; ++t) {
            S4[2 * PL4 + base + t] =
                make_float4(hsA[4 * t], hsA[4 * t + 1], hsA[4 * t + 2], hsA[4 * t + 3]);
            S4[3 * PL4 + base + t] =
                make_float4(hsB[4 * t], hsB[4 * t + 1], hsB[4 * t + 2], hsB[4 * t + 3]);
        }
    }
    __syncthreads();

    // ---------------- Phase C: vertical sums + finale -----------------------
    // 256 threads: ox = tid&63, oy0 = (tid>>6)*8 -> 8 px each.
    {
        const int ox  = tid & 63;
        const int oy0 = (tid >> 6) * 8;
        float ca[24], cbv[24];
        #pragma unroll
        for (int j = 0; j < 24; ++j) {
            ca[j]  = Sf[2 * PL + (oy0 + j) * STRD + ox];
            cbv[j] = Sf[3 * PL + (oy0 + j) * STRD + ox];
        }
        float sa = 0.f, sb = 0.f;
        #pragma unroll
        for (int j = 0; j < 17; ++j) { sa += ca[j]; sb += cbv[j]; }
        #pragma unroll
        for (int o = 0; o < 8; ++o) {
            if (o) {
                sa += ca[o + 16] - ca[o - 1];
                sb += cbv[o + 16] - cbv[o - 1];
            }
            const size_t gp = (size_t)(ty0 + oy0 + o) * W + (tx0 + ox);
            O[plane + gp] = sa * INV_AREA * Ic[gp] + sb * INV_AREA;
        }
    }
}

extern "C" void kernel_launch(void* const* d_in, const int* in_sizes, int n_in,
                              void* d_out, int out_size, void* d_ws, size_t ws_size,
                              hipStream_t stream) {
    const int H = 1024, W = 1024;
    if (n_in < 2) return;
    const long long npx = (long long)H * W;
    const long long n0 = in_sizes[0];
    if (n0 <= 0 || (n0 % npx) != 0) return;
    if ((long long)out_size != n0) return;
    if (in_sizes[1] != in_sizes[0]) return;
    const int NP = (int)(n0 / npx);

    const float* p = (const float*)d_in[0];   // input_img
    const float* I = (const float*)d_in[1];   // guide_img
    float* out = (float*)d_out;

    dim3 grid(W / TW, H / TH, NP);
    gf_fused<<<grid, 256, 0, stream>>>(p, I, out, H, W);
}

// Round 16
// 152.582 us; speedup vs baseline: 1.4194x; 1.4194x over previous
//
#include <hip/hip_runtime.h>

// Guided filter r=8 (K=17), eps=0.1, (8,3,1024,1024); f32 in / f32 out.
// V8 = R11 (best, 196us) + three surgical cuts:
//   1. B1 ab-math: fold means into 289-scaled form; divide -> v_rcp_f32.
//      a = (289*s2 - s0*s1) * rcp(289*s3 - s0^2 + 289^2*eps)
//      b = (s1 - a*s0) * (1/289)          (saves ~170 VALU/thread in B1)
//   2. B1/B2 thread map from R12 (isolated from its XCD-swizzle regression):
//      vr=(tid&15)+16*(tid>>6), u4=(tid>>4)&3 -> b128 phases at exact
//      2-lanes-per-bank-quad (minimal).
//   3. Epilogue: out = INV_AREA * fma(sa, I, sb).
//
// Structure (per 32x32 tile, 256 threads, LDS 4 planes [48][68] f32 = 52.2 KB):
//   A : vertical 17-tap sliding sums {I,p,Ip,II} (28-row reg window) -> LDS
//   B1: horizontal 17-sums (b128) -> a,b (12/thread) -> overwrite planes 0,1
//   B2: horizontal 17-sums of a,b -> planes 2,3
//   C : vertical 17-sums + finale

#define TW 32
#define TH 32
#define STRD 68                    // words; 272 B rows
#define VROWS 48
#define PL (VROWS * STRD)          // 3264 words/plane
#define PL4 (PL / 4)               // 816 float4/plane
#define INV_AREA (1.0f / 289.0f)

__device__ __forceinline__ int refl1024(int v) {
    v = (v < 0) ? -v : v;
    v = (v > 1023) ? 2046 - v : v;
    if (v < 0) v = 0;
    if (v > 1023) v = 1023;
    return v;
}

__global__ __launch_bounds__(256) void gf_fused(
    const float* __restrict__ P, const float* __restrict__ I,
    float* __restrict__ O, int H, int W)
{
    __shared__ __align__(16) float4 S4[4 * PL4];   // 52224 B
    float* __restrict__ Sf = (float*)S4;

    const int tid = threadIdx.x;
    const int tx0 = blockIdx.x * TW;
    const int ty0 = blockIdx.y * TH;
    const size_t plane = (size_t)blockIdx.z * H * W;
    const float* __restrict__ Ic = I + plane;
    const float* __restrict__ Pc = P + plane;

    // ---------------- Phase A: vertical sliding sums ------------------------
    {
        const int vc = tid & 63;                                   // vs col
        const int ck = __builtin_amdgcn_readfirstlane(tid >> 6);   // wave-uniform
        const int r0 = ck * 12;
        const int gx = refl1024(tx0 + vc - 16);

        float vI[28], vP[28];
        #pragma unroll
        for (int j = 0; j < 28; ++j) {
            const int gy = refl1024(ty0 + r0 - 16 + j);            // scalar
            const float* __restrict__ rI = Ic + (size_t)gy * W;    // SGPR base
            const float* __restrict__ rP = Pc + (size_t)gy * W;
            vI[j] = rI[gx];
            vP[j] = rP[gx];
        }
        float s0 = 0.f, s1 = 0.f, s2 = 0.f, s3 = 0.f;
        #pragma unroll
        for (int j = 0; j < 17; ++j) {
            s0 += vI[j]; s1 += vP[j];
            s2 += vI[j] * vP[j];
            s3 += vI[j] * vI[j];
        }
        Sf[0 * PL + r0 * STRD + vc] = s0;
        Sf[1 * PL + r0 * STRD + vc] = s1;
        Sf[2 * PL + r0 * STRD + vc] = s2;
        Sf[3 * PL + r0 * STRD + vc] = s3;
        #pragma unroll
        for (int o = 1; o < 12; ++o) {
            const float ni = vI[o + 16], oi = vI[o - 1];
            const float np_ = vP[o + 16], op_ = vP[o - 1];
            s0 += ni - oi;
            s1 += np_ - op_;
            s2 += ni * np_ - oi * op_;
            s3 += ni * ni - oi * oi;
            Sf[0 * PL + (r0 + o) * STRD + vc] = s0;
            Sf[1 * PL + (r0 + o) * STRD + vc] = s1;
            Sf[2 * PL + (r0 + o) * STRD + vc] = s2;
            Sf[3 * PL + (r0 + o) * STRD + vc] = s3;
        }
    }
    __syncthreads();

    // ---------------- Phase B1: horizontal sums -> a,b ----------------------
    const int vr = (tid & 15) + ((tid >> 6) << 4);   // 0..47 (tid<192)
    const int u4 = (tid >> 4) & 3;                   // col-block (12 ab cols)
    float oa[12], ob[12];
    if (tid < 192) {
        float sm[4][12];
        #pragma unroll
        for (int q = 0; q < 4; ++q) {
            float vv[28];
            #pragma unroll
            for (int t = 0; t < 7; ++t) {
                const float4 w = S4[q * PL4 + vr * 17 + u4 * 3 + t];
                vv[4 * t + 0] = w.x; vv[4 * t + 1] = w.y;
                vv[4 * t + 2] = w.z; vv[4 * t + 3] = w.w;
            }
            float sacc = 0.f;
            #pragma unroll
            for (int j = 0; j < 17; ++j) sacc += vv[j];
            sm[q][0] = sacc;
            #pragma unroll
            for (int o = 1; o < 12; ++o) {
                sacc += vv[o + 16] - vv[o - 1];
                sm[q][o] = sacc;
            }
        }
        #pragma unroll
        for (int o = 0; o < 12; ++o) {
            const float s0 = sm[0][o], s1 = sm[1][o];
            const float s2 = sm[2][o], s3 = sm[3][o];
            // a = cov/(var+eps), scaled by 289^2:
            const float num = fmaf(289.0f, s2, -s0 * s1);
            const float den = fmaf(289.0f, s3, -s0 * s0) + 8352.1f; // 289^2*0.1
            const float av  = num * __builtin_amdgcn_rcpf(den);
            oa[o] = av;
            ob[o] = fmaf(-av, s0, s1) * INV_AREA;
        }
    }
    __syncthreads();
    if (tid < 192) {
        #pragma unroll
        for (int t = 0; t < 3; ++t) {
            S4[0 * PL4 + vr * 17 + u4 * 3 + t] =
                make_float4(oa[4 * t], oa[4 * t + 1], oa[4 * t + 2], oa[4 * t + 3]);
            S4[1 * PL4 + vr * 17 + u4 * 3 + t] =
                make_float4(ob[4 * t], ob[4 * t + 1], ob[4 * t + 2], ob[4 * t + 3]);
        }
    }
    __syncthreads();

    // ---------------- Phase B2: horizontal sums of a,b -> planes 2,3 --------
    if (tid < 192) {
        float va[24], vb[24];
        #pragma unroll
        for (int t = 0; t < 6; ++t) {
            const float4 wa = S4[0 * PL4 + vr * 17 + u4 * 2 + t];
            const float4 wb = S4[1 * PL4 + vr * 17 + u4 * 2 + t];
            va[4 * t + 0] = wa.x; va[4 * t + 1] = wa.y;
            va[4 * t + 2] = wa.z; va[4 * t + 3] = wa.w;
            vb[4 * t + 0] = wb.x; vb[4 * t + 1] = wb.y;
            vb[4 * t + 2] = wb.z; vb[4 * t + 3] = wb.w;
        }
        float hsA[8], hsB[8];
        float sa = 0.f, sb = 0.f;
        #pragma unroll
        for (int j = 0; j < 17; ++j) { sa += va[j]; sb += vb[j]; }
        hsA[0] = sa; hsB[0] = sb;
        #pragma unroll
        for (int o = 1; o < 8; ++o) {
            sa += va[o + 16] - va[o - 1];
            sb += vb[o + 16] - vb[o - 1];
            hsA[o] = sa; hsB[o] = sb;
        }
        #pragma unroll
        for (int t = 0; t < 2; ++t) {
            S4[2 * PL4 + vr * 17 + u4 * 2 + t] =
                make_float4(hsA[4 * t], hsA[4 * t + 1], hsA[4 * t + 2], hsA[4 * t + 3]);
            S4[3 * PL4 + vr * 17 + u4 * 2 + t] =
                make_float4(hsB[4 * t], hsB[4 * t + 1], hsB[4 * t + 2], hsB[4 * t + 3]);
        }
    }
    __syncthreads();

    // ---------------- Phase C: vertical sums + finale -----------------------
    {
        const int ox  = tid & 31;
        const int oy0 = (tid >> 5) * 4;    // 0,4,...,28
        float sa = 0.f, sb = 0.f;
        #pragma unroll
        for (int j = 0; j < 17; ++j) {
            sa += Sf[2 * PL + (oy0 + j) * STRD + ox];
            sb += Sf[3 * PL + (oy0 + j) * STRD + ox];
        }
        #pragma unroll
        for (int o = 0; o < 4; ++o) {
            if (o) {
                sa += Sf[2 * PL + (oy0 + o + 16) * STRD + ox]
                    - Sf[2 * PL + (oy0 + o - 1) * STRD + ox];
                sb += Sf[3 * PL + (oy0 + o + 16) * STRD + ox]
                    - Sf[3 * PL + (oy0 + o - 1) * STRD + ox];
            }
            const size_t gp = (size_t)(ty0 + oy0 + o) * W + (tx0 + ox);
            O[plane + gp] = INV_AREA * fmaf(sa, Ic[gp], sb);
        }
    }
}

extern "C" void kernel_launch(void* const* d_in, const int* in_sizes, int n_in,
                              void* d_out, int out_size, void* d_ws, size_t ws_size,
                              hipStream_t stream) {
    const int H = 1024, W = 1024;
    if (n_in < 2) return;
    const long long npx = (long long)H * W;
    const long long n0 = in_sizes[0];
    if (n0 <= 0 || (n0 % npx) != 0) return;
    if ((long long)out_size != n0) return;
    if (in_sizes[1] != in_sizes[0]) return;
    const int NP = (int)(n0 / npx);

    const float* p = (const float*)d_in[0];   // input_img
    const float* I = (const float*)d_in[1];   // guide_img
    float* out = (float*)d_out;

    dim3 grid(W / TW, H / TH, NP);
    gf_fused<<<grid, 256, 0, stream>>>(p, I, out, H, W);
}